// Round 1
// baseline (611.891 us; speedup 1.0000x reference)
//
#include <hip/hip_runtime.h>
#include <hip/hip_bf16.h>
#include <type_traits>

#define BATCH 2
#define SEQ   8192
#define CH    1024
#define NH    16
#define BLK   64
#define WIN   192
#define NBL   128
#define DH    64
#define MR    (BATCH*SEQ)   // 16384

typedef __bf16 bf16x8 __attribute__((ext_vector_type(8)));
typedef float  f32x4  __attribute__((ext_vector_type(4)));

__device__ __forceinline__ f32x4 zero4() {
    f32x4 z; z[0]=0.f; z[1]=0.f; z[2]=0.f; z[3]=0.f; return z;
}

union Pack4 { __hip_bfloat16 h[4]; uint2 u; };
union Pack8 { __hip_bfloat16 h[8]; uint4 u; };

// C[M,N] = alpha * (A[M,K] @ Wm[N,K]^T + bias[N]) ; M=MR, N=K=CH fixed.
template<typename AT, typename OT>
__global__ __launch_bounds__(256) void gemm_bt(
    const AT* __restrict__ A, const float* __restrict__ Wm,
    const float* __restrict__ bias, OT* __restrict__ out, float alpha)
{
    constexpr int BM = 128, BN = 128, BK = 32, LDA = BK + 8;
    __shared__ __hip_bfloat16 As[BM][LDA];
    __shared__ __hip_bfloat16 Bs[BN][LDA];

    const int tid  = threadIdx.x;
    const int m0   = blockIdx.y * BM;
    const int n0   = blockIdx.x * BN;
    const int wid  = tid >> 6;
    const int lane = tid & 63;
    const int quad = lane >> 4;
    const int l16  = lane & 15;
    const int wr   = wid >> 1, wc = wid & 1;

    f32x4 acc[4][4];
    #pragma unroll
    for (int i = 0; i < 4; i++)
        #pragma unroll
        for (int j = 0; j < 4; j++) acc[i][j] = zero4();

    for (int k0 = 0; k0 < CH; k0 += BK) {
        // ---- stage A tile (BM x BK) into bf16 LDS
        if constexpr (std::is_same<AT, float>::value) {
            #pragma unroll
            for (int it = 0; it < 4; it++) {
                int idx = tid + it * 256;            // 0..1023 float4 chunks
                int row = idx >> 3, seg = idx & 7;
                const float4 x = *reinterpret_cast<const float4*>(
                    A + (size_t)(m0 + row) * CH + k0 + seg * 4);
                Pack4 p;
                p.h[0] = __float2bfloat16(x.x); p.h[1] = __float2bfloat16(x.y);
                p.h[2] = __float2bfloat16(x.z); p.h[3] = __float2bfloat16(x.w);
                *reinterpret_cast<uint2*>(&As[row][seg * 4]) = p.u;
            }
        } else {
            #pragma unroll
            for (int it = 0; it < 2; it++) {
                int idx = tid + it * 256;            // 0..511 chunks of 8 bf16
                int row = idx >> 2, seg = idx & 3;
                *reinterpret_cast<uint4*>(&As[row][seg * 8]) =
                    *reinterpret_cast<const uint4*>(
                        A + (size_t)(m0 + row) * CH + k0 + seg * 8);
            }
        }
        // ---- stage B tile = weights (BN x BK), fp32 -> bf16
        #pragma unroll
        for (int it = 0; it < 4; it++) {
            int idx = tid + it * 256;
            int row = idx >> 3, seg = idx & 7;
            const float4 x = *reinterpret_cast<const float4*>(
                Wm + (size_t)(n0 + row) * CH + k0 + seg * 4);
            Pack4 p;
            p.h[0] = __float2bfloat16(x.x); p.h[1] = __float2bfloat16(x.y);
            p.h[2] = __float2bfloat16(x.z); p.h[3] = __float2bfloat16(x.w);
            *reinterpret_cast<uint2*>(&Bs[row][seg * 4]) = p.u;
        }
        __syncthreads();

        bf16x8 af[4], bfr[4];
        #pragma unroll
        for (int i = 0; i < 4; i++)
            af[i] = *reinterpret_cast<const bf16x8*>(&As[wr * 64 + i * 16 + l16][quad * 8]);
        #pragma unroll
        for (int j = 0; j < 4; j++)
            bfr[j] = *reinterpret_cast<const bf16x8*>(&Bs[wc * 64 + j * 16 + l16][quad * 8]);
        #pragma unroll
        for (int i = 0; i < 4; i++)
            #pragma unroll
            for (int j = 0; j < 4; j++)
                acc[i][j] = __builtin_amdgcn_mfma_f32_16x16x32_bf16(
                    af[i], bfr[j], acc[i][j], 0, 0, 0);
        __syncthreads();
    }

    // ---- epilogue: out = alpha*(acc + bias)
    #pragma unroll
    for (int j = 0; j < 4; j++) {
        const int col = n0 + wc * 64 + j * 16 + l16;
        const float bv = bias[col];
        #pragma unroll
        for (int i = 0; i < 4; i++) {
            #pragma unroll
            for (int r = 0; r < 4; r++) {
                const int row = m0 + wr * 64 + i * 16 + quad * 4 + r;
                float v = alpha * (acc[i][j][r] + bv);
                if constexpr (std::is_same<OT, float>::value)
                    out[(size_t)row * CH + col] = v;
                else
                    out[(size_t)row * CH + col] = __float2bfloat16(v);
            }
        }
    }
}

// One workgroup per (b, h, block-of-64-queries). Window of 192 keys
// starting at t0-64 (clamped loads, analytic masking).
__global__ __launch_bounds__(256) void attn_kernel(
    const __hip_bfloat16* __restrict__ qg,
    const __hip_bfloat16* __restrict__ kg,
    const __hip_bfloat16* __restrict__ vg,
    __hip_bfloat16* __restrict__ ctx)
{
    // LDS plan (bf16, pad +8):
    //   qs [64][72]   @0      (9216 B)
    //   ks [192][72]  @9216   (27648 B)
    //   vt [64][200]  @36864  (25600 B)
    //   ps [64][200]  @0      (aliases qs+ks after scores are consumed)
    __shared__ alignas(16) char smem[62464];
    auto qs = reinterpret_cast<__hip_bfloat16(*)[72]>(smem);
    auto ks = reinterpret_cast<__hip_bfloat16(*)[72]>(smem + 9216);
    auto vt = reinterpret_cast<__hip_bfloat16(*)[200]>(smem + 36864);
    auto ps = reinterpret_cast<__hip_bfloat16(*)[200]>(smem);

    const int blk = blockIdx.x;
    const int n = blk & (NBL - 1);
    const int h = (blk >> 7) & (NH - 1);
    const int b = blk >> 11;
    const int t0  = n * BLK;
    const int kst = t0 - 64;          // raw window start (may be <0)
    const int tid = threadIdx.x;
    const size_t baseBH = (size_t)b * SEQ * CH + (size_t)h * DH;

    // ---- stage q (64 rows x 64 d)
    #pragma unroll
    for (int it = 0; it < 2; it++) {
        int c = tid + it * 256;
        int row = c >> 3, seg = c & 7;
        *reinterpret_cast<uint4*>(&qs[row][seg * 8]) =
            *reinterpret_cast<const uint4*>(qg + baseBH + (size_t)(t0 + row) * CH + seg * 8);
    }
    // ---- stage k (192 rows x 64 d), clamped
    #pragma unroll
    for (int it = 0; it < 6; it++) {
        int c = tid + it * 256;
        int row = c >> 3, seg = c & 7;
        int tr = kst + row; tr = tr < 0 ? 0 : (tr >= SEQ ? SEQ - 1 : tr);
        *reinterpret_cast<uint4*>(&ks[row][seg * 8]) =
            *reinterpret_cast<const uint4*>(kg + baseBH + (size_t)tr * CH + seg * 8);
    }
    // ---- stage v transposed: vt[d][j]
    #pragma unroll
    for (int it = 0; it < 6; it++) {
        int c = tid + it * 256;
        int j = c % WIN, seg = c / WIN;
        int tr = kst + j; tr = tr < 0 ? 0 : (tr >= SEQ ? SEQ - 1 : tr);
        Pack8 p;
        p.u = *reinterpret_cast<const uint4*>(vg + baseBH + (size_t)tr * CH + seg * 8);
        #pragma unroll
        for (int e = 0; e < 8; e++) vt[seg * 8 + e][j] = p.h[e];
    }
    __syncthreads();

    const int wid = tid >> 6, lane = tid & 63, quad = lane >> 4, l16 = lane & 15;

    // ---- scores: wave wid owns query rows [wid*16, wid*16+16); 12 n-tiles of 16 keys
    f32x4 sc[12];
    #pragma unroll
    for (int j = 0; j < 12; j++) sc[j] = zero4();
    #pragma unroll
    for (int kk = 0; kk < 2; kk++) {
        bf16x8 aq = *reinterpret_cast<const bf16x8*>(&qs[wid * 16 + l16][kk * 32 + quad * 8]);
        #pragma unroll
        for (int j = 0; j < 12; j++) {
            bf16x8 bk = *reinterpret_cast<const bf16x8*>(&ks[j * 16 + l16][kk * 32 + quad * 8]);
            sc[j] = __builtin_amdgcn_mfma_f32_16x16x32_bf16(aq, bk, sc[j], 0, 0, 0);
        }
    }
    __syncthreads();   // everyone done reading qs/ks before ps (alias) is written

    // ---- softmax: row = wid*16 + quad*4 + r lives entirely in this 16-lane quad
    #pragma unroll
    for (int r = 0; r < 4; r++) {
        float s[12];
        float mx = -3.0e38f;
        #pragma unroll
        for (int j = 0; j < 12; j++) {
            int col = j * 16 + l16;
            int tr = kst + col;
            bool valid = (tr >= 0) && (tr < SEQ);
            s[j] = valid ? sc[j][r] : -3.0e38f;
            mx = fmaxf(mx, s[j]);
        }
        #pragma unroll
        for (int o = 1; o < 16; o <<= 1) mx = fmaxf(mx, __shfl_xor(mx, o, 64));
        float sum = 0.f;
        #pragma unroll
        for (int j = 0; j < 12; j++) {
            float e = __expf(s[j] - mx);
            s[j] = e;
            sum += e;
        }
        #pragma unroll
        for (int o = 1; o < 16; o <<= 1) sum += __shfl_xor(sum, o, 64);
        const float inv = 1.f / sum;
        const int row = wid * 16 + quad * 4 + r;
        #pragma unroll
        for (int j = 0; j < 12; j++)
            ps[row][j * 16 + l16] = __float2bfloat16(s[j] * inv);
    }
    __syncthreads();

    // ---- PV: out rows = wave's 16 rows, 4 n-tiles over d, K=192 in 6 steps
    f32x4 oa[4];
    #pragma unroll
    for (int j = 0; j < 4; j++) oa[j] = zero4();
    #pragma unroll
    for (int kk = 0; kk < 6; kk++) {
        bf16x8 ap = *reinterpret_cast<const bf16x8*>(&ps[wid * 16 + l16][kk * 32 + quad * 8]);
        #pragma unroll
        for (int j = 0; j < 4; j++) {
            bf16x8 bv = *reinterpret_cast<const bf16x8*>(&vt[j * 16 + l16][kk * 32 + quad * 8]);
            oa[j] = __builtin_amdgcn_mfma_f32_16x16x32_bf16(ap, bv, oa[j], 0, 0, 0);
        }
    }
    #pragma unroll
    for (int j = 0; j < 4; j++) {
        const int d = j * 16 + l16;
        #pragma unroll
        for (int r = 0; r < 4; r++) {
            const int i = wid * 16 + quad * 4 + r;
            ctx[baseBH + (size_t)(t0 + i) * CH + d] = __float2bfloat16(oa[j][r]);
        }
    }
}

extern "C" void kernel_launch(void* const* d_in, const int* in_sizes, int n_in,
                              void* d_out, int out_size, void* d_ws, size_t ws_size,
                              hipStream_t stream)
{
    const float* query = (const float*)d_in[0];
    const float* key_i = (const float*)d_in[1];
    const float* value = (const float*)d_in[2];
    const float* Wq = (const float*)d_in[3];
    const float* bq = (const float*)d_in[4];
    const float* Wk = (const float*)d_in[5];
    const float* bk = (const float*)d_in[6];
    const float* Wv = (const float*)d_in[7];
    const float* bv = (const float*)d_in[8];
    const float* Wo = (const float*)d_in[9];
    const float* bo = (const float*)d_in[10];
    float* out = (float*)d_out;

    const size_t NELEM = (size_t)MR * CH;           // 16,777,216
    __hip_bfloat16* qb = (__hip_bfloat16*)d_ws;
    __hip_bfloat16* kb = qb + NELEM;
    __hip_bfloat16* vb = kb + NELEM;
    __hip_bfloat16* cb = vb + NELEM;

    dim3 ggrid(CH / 128, MR / 128);                 // (8, 128)
    const float qscale = 0.125f;                    // D^-0.5 = 64^-0.5

    gemm_bt<float, __hip_bfloat16><<<ggrid, 256, 0, stream>>>(query, Wq, bq, qb, qscale);
    gemm_bt<float, __hip_bfloat16><<<ggrid, 256, 0, stream>>>(key_i, Wk, bk, kb, 1.0f);
    gemm_bt<float, __hip_bfloat16><<<ggrid, 256, 0, stream>>>(value, Wv, bv, vb, 1.0f);

    attn_kernel<<<BATCH * NH * NBL, 256, 0, stream>>>(qb, kb, vb, cb);

    gemm_bt<__hip_bfloat16, float><<<ggrid, 256, 0, stream>>>(cb, Wo, bo, out, 1.0f);
}

// Round 2
// 529.734 us; speedup vs baseline: 1.1551x; 1.1551x over previous
//
#include <hip/hip_runtime.h>
#include <hip/hip_bf16.h>
#include <type_traits>

#define BATCH 2
#define SEQ   8192
#define CH    1024
#define NH    16
#define BLK   64
#define WIN   192
#define NBL   128
#define DH    64
#define MR    (BATCH*SEQ)   // 16384

typedef __bf16 bf16x8 __attribute__((ext_vector_type(8)));
typedef float  f32x4  __attribute__((ext_vector_type(4)));

__device__ __forceinline__ f32x4 zero4() {
    f32x4 z; z[0]=0.f; z[1]=0.f; z[2]=0.f; z[3]=0.f; return z;
}

union Pack4 { __hip_bfloat16 h[4]; uint2 u; };
union Pack8 { __hip_bfloat16 h[8]; uint4 u; };

typedef const __attribute__((address_space(1))) unsigned int* gas_ptr;
typedef       __attribute__((address_space(3))) unsigned int* las_ptr;

__device__ __forceinline__ void gload_lds16(const __hip_bfloat16* g, __hip_bfloat16* l) {
    __builtin_amdgcn_global_load_lds((gas_ptr)(const void*)g, (las_ptr)(void*)l, 16, 0, 0);
}

// ---- fp32 -> bf16 pack, 8 elements/thread
__global__ __launch_bounds__(256) void pack_bf16(
    const float* __restrict__ src, __hip_bfloat16* __restrict__ dst, int n8)
{
    int i = blockIdx.x * 256 + threadIdx.x;
    if (i >= n8) return;
    const float4* s = reinterpret_cast<const float4*>(src);
    float4 a = s[2 * i], b = s[2 * i + 1];
    Pack8 p;
    p.h[0] = __float2bfloat16(a.x); p.h[1] = __float2bfloat16(a.y);
    p.h[2] = __float2bfloat16(a.z); p.h[3] = __float2bfloat16(a.w);
    p.h[4] = __float2bfloat16(b.x); p.h[5] = __float2bfloat16(b.y);
    p.h[6] = __float2bfloat16(b.z); p.h[7] = __float2bfloat16(b.w);
    reinterpret_cast<uint4*>(dst)[i] = p.u;
}

// C[M,N] = alpha * (A[M,K] @ Wb[N,K]^T + bias[N]); M=MR, N=K=CH.
// m97 structure: bf16 operands, global_load_lds width-16 staging into
// UNPADDED linear LDS (wave-uniform base + lane*16 semantics), 16 MFMA/k-step.
template<typename OT>
__global__ __launch_bounds__(256) void gemm_bt_bf16(
    const __hip_bfloat16* __restrict__ A, const __hip_bfloat16* __restrict__ Wb,
    const float* __restrict__ bias, OT* __restrict__ out, float alpha)
{
    __shared__ alignas(16) __hip_bfloat16 As[128 * 32];
    __shared__ alignas(16) __hip_bfloat16 Bs[128 * 32];

    const int tid  = threadIdx.x;
    const int m0   = blockIdx.y * 128;
    const int n0   = blockIdx.x * 128;
    const int wid  = tid >> 6;
    const int lane = tid & 63;
    const int quad = lane >> 4;
    const int l16  = lane & 15;
    const int wr   = wid >> 1, wc = wid & 1;

    // staging: idx in [0,512): row = idx>>2, k-seg = (idx&3)*8
    const int r0 = tid >> 2;
    const int sg = (tid & 3) * 8;
    const __hip_bfloat16* a0 = A  + (size_t)(m0 + r0)      * CH + sg;
    const __hip_bfloat16* a1 = A  + (size_t)(m0 + r0 + 64) * CH + sg;
    const __hip_bfloat16* b0 = Wb + (size_t)(n0 + r0)      * CH + sg;
    const __hip_bfloat16* b1 = Wb + (size_t)(n0 + r0 + 64) * CH + sg;
    __hip_bfloat16* la0 = As + tid * 8;
    __hip_bfloat16* la1 = As + (tid + 256) * 8;
    __hip_bfloat16* lb0 = Bs + tid * 8;
    __hip_bfloat16* lb1 = Bs + (tid + 256) * 8;

    f32x4 acc[4][4];
    #pragma unroll
    for (int i = 0; i < 4; i++)
        #pragma unroll
        for (int j = 0; j < 4; j++) acc[i][j] = zero4();

    for (int k0 = 0; k0 < CH; k0 += 32) {
        gload_lds16(a0 + k0, la0);
        gload_lds16(a1 + k0, la1);
        gload_lds16(b0 + k0, lb0);
        gload_lds16(b1 + k0, lb1);
        __syncthreads();          // drains vmcnt, then barrier

        bf16x8 af[4], bfr[4];
        #pragma unroll
        for (int i = 0; i < 4; i++)
            af[i] = *reinterpret_cast<const bf16x8*>(
                As + (wr * 64 + i * 16 + l16) * 32 + quad * 8);
        #pragma unroll
        for (int j = 0; j < 4; j++)
            bfr[j] = *reinterpret_cast<const bf16x8*>(
                Bs + (wc * 64 + j * 16 + l16) * 32 + quad * 8);
        #pragma unroll
        for (int i = 0; i < 4; i++)
            #pragma unroll
            for (int j = 0; j < 4; j++)
                acc[i][j] = __builtin_amdgcn_mfma_f32_16x16x32_bf16(
                    af[i], bfr[j], acc[i][j], 0, 0, 0);
        __syncthreads();
    }

    #pragma unroll
    for (int j = 0; j < 4; j++) {
        const int col = n0 + wc * 64 + j * 16 + l16;
        const float bv = bias[col];
        #pragma unroll
        for (int i = 0; i < 4; i++) {
            #pragma unroll
            for (int r = 0; r < 4; r++) {
                const int row = m0 + wr * 64 + i * 16 + quad * 4 + r;
                float v = alpha * (acc[i][j][r] + bv);
                if constexpr (std::is_same<OT, float>::value)
                    out[(size_t)row * CH + col] = v;
                else
                    out[(size_t)row * CH + col] = __float2bfloat16(v);
            }
        }
    }
}

// One workgroup per (b, h, block-of-64-queries). Window of 192 keys
// starting at t0-64 (clamped loads, analytic masking).
__global__ __launch_bounds__(256) void attn_kernel(
    const __hip_bfloat16* __restrict__ qg,
    const __hip_bfloat16* __restrict__ kg,
    const __hip_bfloat16* __restrict__ vg,
    __hip_bfloat16* __restrict__ ctx)
{
    __shared__ alignas(16) char smem[62464];
    auto qs = reinterpret_cast<__hip_bfloat16(*)[72]>(smem);
    auto ks = reinterpret_cast<__hip_bfloat16(*)[72]>(smem + 9216);
    auto vt = reinterpret_cast<__hip_bfloat16(*)[200]>(smem + 36864);
    auto ps = reinterpret_cast<__hip_bfloat16(*)[200]>(smem);

    const int blk = blockIdx.x;
    const int n = blk & (NBL - 1);
    const int h = (blk >> 7) & (NH - 1);
    const int b = blk >> 11;
    const int t0  = n * BLK;
    const int kst = t0 - 64;
    const int tid = threadIdx.x;
    const size_t baseBH = (size_t)b * SEQ * CH + (size_t)h * DH;

    #pragma unroll
    for (int it = 0; it < 2; it++) {
        int c = tid + it * 256;
        int row = c >> 3, seg = c & 7;
        *reinterpret_cast<uint4*>(&qs[row][seg * 8]) =
            *reinterpret_cast<const uint4*>(qg + baseBH + (size_t)(t0 + row) * CH + seg * 8);
    }
    #pragma unroll
    for (int it = 0; it < 6; it++) {
        int c = tid + it * 256;
        int row = c >> 3, seg = c & 7;
        int tr = kst + row; tr = tr < 0 ? 0 : (tr >= SEQ ? SEQ - 1 : tr);
        *reinterpret_cast<uint4*>(&ks[row][seg * 8]) =
            *reinterpret_cast<const uint4*>(kg + baseBH + (size_t)tr * CH + seg * 8);
    }
    #pragma unroll
    for (int it = 0; it < 6; it++) {
        int c = tid + it * 256;
        int j = c % WIN, seg = c / WIN;
        int tr = kst + j; tr = tr < 0 ? 0 : (tr >= SEQ ? SEQ - 1 : tr);
        Pack8 p;
        p.u = *reinterpret_cast<const uint4*>(vg + baseBH + (size_t)tr * CH + seg * 8);
        #pragma unroll
        for (int e = 0; e < 8; e++) vt[seg * 8 + e][j] = p.h[e];
    }
    __syncthreads();

    const int wid = tid >> 6, lane = tid & 63, quad = lane >> 4, l16 = lane & 15;

    f32x4 sc[12];
    #pragma unroll
    for (int j = 0; j < 12; j++) sc[j] = zero4();
    #pragma unroll
    for (int kk = 0; kk < 2; kk++) {
        bf16x8 aq = *reinterpret_cast<const bf16x8*>(&qs[wid * 16 + l16][kk * 32 + quad * 8]);
        #pragma unroll
        for (int j = 0; j < 12; j++) {
            bf16x8 bk = *reinterpret_cast<const bf16x8*>(&ks[j * 16 + l16][kk * 32 + quad * 8]);
            sc[j] = __builtin_amdgcn_mfma_f32_16x16x32_bf16(aq, bk, sc[j], 0, 0, 0);
        }
    }
    __syncthreads();

    #pragma unroll
    for (int r = 0; r < 4; r++) {
        float s[12];
        float mx = -3.0e38f;
        #pragma unroll
        for (int j = 0; j < 12; j++) {
            int col = j * 16 + l16;
            int tr = kst + col;
            bool valid = (tr >= 0) && (tr < SEQ);
            s[j] = valid ? sc[j][r] : -3.0e38f;
            mx = fmaxf(mx, s[j]);
        }
        #pragma unroll
        for (int o = 1; o < 16; o <<= 1) mx = fmaxf(mx, __shfl_xor(mx, o, 64));
        float sum = 0.f;
        #pragma unroll
        for (int j = 0; j < 12; j++) {
            float e = __expf(s[j] - mx);
            s[j] = e;
            sum += e;
        }
        #pragma unroll
        for (int o = 1; o < 16; o <<= 1) sum += __shfl_xor(sum, o, 64);
        const float inv = 1.f / sum;
        const int row = wid * 16 + quad * 4 + r;
        #pragma unroll
        for (int j = 0; j < 12; j++)
            ps[row][j * 16 + l16] = __float2bfloat16(s[j] * inv);
    }
    __syncthreads();

    f32x4 oa[4];
    #pragma unroll
    for (int j = 0; j < 4; j++) oa[j] = zero4();
    #pragma unroll
    for (int kk = 0; kk < 6; kk++) {
        bf16x8 ap = *reinterpret_cast<const bf16x8*>(&ps[wid * 16 + l16][kk * 32 + quad * 8]);
        #pragma unroll
        for (int j = 0; j < 4; j++) {
            bf16x8 bv = *reinterpret_cast<const bf16x8*>(&vt[j * 16 + l16][kk * 32 + quad * 8]);
            oa[j] = __builtin_amdgcn_mfma_f32_16x16x32_bf16(ap, bv, oa[j], 0, 0, 0);
        }
    }
    #pragma unroll
    for (int j = 0; j < 4; j++) {
        const int d = j * 16 + l16;
        #pragma unroll
        for (int r = 0; r < 4; r++) {
            const int i = wid * 16 + quad * 4 + r;
            ctx[baseBH + (size_t)(t0 + i) * CH + d] = __float2bfloat16(oa[j][r]);
        }
    }
}

extern "C" void kernel_launch(void* const* d_in, const int* in_sizes, int n_in,
                              void* d_out, int out_size, void* d_ws, size_t ws_size,
                              hipStream_t stream)
{
    const float* query = (const float*)d_in[0];
    const float* key_i = (const float*)d_in[1];
    const float* value = (const float*)d_in[2];
    const float* Wq = (const float*)d_in[3];
    const float* bq = (const float*)d_in[4];
    const float* Wk = (const float*)d_in[5];
    const float* bk = (const float*)d_in[6];
    const float* Wv = (const float*)d_in[7];
    const float* bv = (const float*)d_in[8];
    const float* Wo = (const float*)d_in[9];
    const float* bo = (const float*)d_in[10];
    float* out = (float*)d_out;

    const size_t NELEM = (size_t)MR * CH;   // 16,777,216
    const size_t WELEM = (size_t)CH * CH;   // 1,048,576

    // ws layout (104 MiB used):
    //   S0: xv (phase 1-2) -> cb (phase 3-4)
    //   S1: qb   S2: kb
    //   S3: packed weights wq|wk|wv|wo (2 MiB each)
    __hip_bfloat16* S0 = (__hip_bfloat16*)d_ws;
    __hip_bfloat16* S1 = S0 + NELEM;
    __hip_bfloat16* S2 = S1 + NELEM;
    __hip_bfloat16* S3 = S2 + NELEM;
    __hip_bfloat16* wqb = S3;
    __hip_bfloat16* wkb = S3 + WELEM;
    __hip_bfloat16* wvb = S3 + 2 * WELEM;
    __hip_bfloat16* wob = S3 + 3 * WELEM;

    // d_out doubles as scratch: xq|xk (bf16) until consumed, then vb.
    __hip_bfloat16* xq = (__hip_bfloat16*)d_out;
    __hip_bfloat16* xk = xq + NELEM;
    __hip_bfloat16* vb = (__hip_bfloat16*)d_out;   // after Q-GEMM consumed xq
    __hip_bfloat16* qb = S1;
    __hip_bfloat16* kb = S2;
    __hip_bfloat16* cb = S0;

    const int nA8 = (int)(NELEM / 8);   // 2,097,152
    const int nW8 = (int)(WELEM / 8);   // 131,072

    pack_bf16<<<nA8 / 256, 256, 0, stream>>>(query, xq, nA8);
    pack_bf16<<<nA8 / 256, 256, 0, stream>>>(key_i, xk, nA8);
    pack_bf16<<<nA8 / 256, 256, 0, stream>>>(value, S0, nA8);
    pack_bf16<<<nW8 / 256, 256, 0, stream>>>(Wq, wqb, nW8);
    pack_bf16<<<nW8 / 256, 256, 0, stream>>>(Wk, wkb, nW8);
    pack_bf16<<<nW8 / 256, 256, 0, stream>>>(Wv, wvb, nW8);
    pack_bf16<<<nW8 / 256, 256, 0, stream>>>(Wo, wob, nW8);

    dim3 ggrid(CH / 128, MR / 128);     // (8, 128)
    const float qscale = 0.125f;        // 64^-0.5

    gemm_bt_bf16<__hip_bfloat16><<<ggrid, 256, 0, stream>>>(xq, wqb, bq, qb, qscale);
    gemm_bt_bf16<__hip_bfloat16><<<ggrid, 256, 0, stream>>>(xk, wkb, bk, kb, 1.0f);
    gemm_bt_bf16<__hip_bfloat16><<<ggrid, 256, 0, stream>>>(S0, wvb, bv, vb, 1.0f);

    attn_kernel<<<BATCH * NH * NBL, 256, 0, stream>>>(qb, kb, vb, cb);

    gemm_bt_bf16<float><<<ggrid, 256, 0, stream>>>(cb, wob, bo, out, 1.0f);
}

// Round 3
// 501.821 us; speedup vs baseline: 1.2193x; 1.0556x over previous
//
#include <hip/hip_runtime.h>
#include <hip/hip_bf16.h>
#include <type_traits>

#define BATCH 2
#define SEQ   8192
#define CH    1024
#define NH    16
#define BLK   64
#define WIN   192
#define NBL   128
#define DH    64
#define MR    (BATCH*SEQ)   // 16384

typedef __bf16 bf16x8 __attribute__((ext_vector_type(8)));
typedef float  f32x4  __attribute__((ext_vector_type(4)));

__device__ __forceinline__ f32x4 zero4() {
    f32x4 z; z[0]=0.f; z[1]=0.f; z[2]=0.f; z[3]=0.f; return z;
}

union Pack8 { __hip_bfloat16 h[8]; uint4 u; };

typedef const __attribute__((address_space(1))) unsigned int* gas_ptr;
typedef       __attribute__((address_space(3))) unsigned int* las_ptr;

__device__ __forceinline__ void gload_lds16(const __hip_bfloat16* g, __hip_bfloat16* l) {
    __builtin_amdgcn_global_load_lds((gas_ptr)(const void*)g, (las_ptr)(void*)l, 16, 0, 0);
}

// ---- fp32 -> bf16 pack, 8 elements/thread
__global__ __launch_bounds__(256) void pack_bf16(
    const float* __restrict__ src, __hip_bfloat16* __restrict__ dst, int n8)
{
    int i = blockIdx.x * 256 + threadIdx.x;
    if (i >= n8) return;
    const float4* s = reinterpret_cast<const float4*>(src);
    float4 a = s[2 * i], b = s[2 * i + 1];
    Pack8 p;
    p.h[0] = __float2bfloat16(a.x); p.h[1] = __float2bfloat16(a.y);
    p.h[2] = __float2bfloat16(a.z); p.h[3] = __float2bfloat16(a.w);
    p.h[4] = __float2bfloat16(b.x); p.h[5] = __float2bfloat16(b.y);
    p.h[6] = __float2bfloat16(b.z); p.h[7] = __float2bfloat16(b.w);
    reinterpret_cast<uint4*>(dst)[i] = p.u;
}

// ---- GEMM body: C[M,N] = alpha*(A @ Wb^T + bias); 128x128 tile, BK=64,
// global_load_lds width-16 into XOR-swizzled linear LDS (conflict-free b128
// reads despite the lane-contiguous write constraint). K = N = CH.
template<typename OT>
__device__ __forceinline__ void gemm_body(
    const __hip_bfloat16* __restrict__ A, const __hip_bfloat16* __restrict__ Wb,
    const float* __restrict__ bias, OT* __restrict__ out, float alpha,
    __hip_bfloat16* As, __hip_bfloat16* Bs)
{
    const int tid  = threadIdx.x;
    const int m0   = blockIdx.y * 128;
    const int n0   = blockIdx.x * 128;
    const int wid  = tid >> 6;
    const int lane = tid & 63;
    const int quad = lane >> 4;
    const int l16  = lane & 15;
    const int wr   = wid >> 1, wc = wid & 1;

    // staging map: LDS chunk c (16B) holds row r=c>>3, global seg s=(c&7)^(r&7)
    int offA[4], offB[4];
    #pragma unroll
    for (int it = 0; it < 4; it++) {
        int c = tid + it * 256;
        int r = c >> 3;
        int s = (c & 7) ^ (r & 7);
        offA[it] = (m0 + r) * CH + s * 8;
        offB[it] = (n0 + r) * CH + s * 8;
    }

    f32x4 acc[4][4];
    #pragma unroll
    for (int i = 0; i < 4; i++)
        #pragma unroll
        for (int j = 0; j < 4; j++) acc[i][j] = zero4();

    for (int k0 = 0; k0 < CH; k0 += 64) {
        #pragma unroll
        for (int it = 0; it < 4; it++)
            gload_lds16(A + offA[it] + k0, As + (tid + it * 256) * 8);
        #pragma unroll
        for (int it = 0; it < 4; it++)
            gload_lds16(Wb + offB[it] + k0, Bs + (tid + it * 256) * 8);
        __syncthreads();

        #pragma unroll
        for (int kk = 0; kk < 2; kk++) {
            bf16x8 af[4], bfr[4];
            #pragma unroll
            for (int i = 0; i < 4; i++) {
                int r = wr * 64 + i * 16 + l16;
                int chunk = r * 8 + ((kk * 4 + quad) ^ (l16 & 7));
                af[i] = *reinterpret_cast<const bf16x8*>(As + chunk * 8);
            }
            #pragma unroll
            for (int j = 0; j < 4; j++) {
                int r = wc * 64 + j * 16 + l16;
                int chunk = r * 8 + ((kk * 4 + quad) ^ (l16 & 7));
                bfr[j] = *reinterpret_cast<const bf16x8*>(Bs + chunk * 8);
            }
            #pragma unroll
            for (int i = 0; i < 4; i++)
                #pragma unroll
                for (int j = 0; j < 4; j++)
                    acc[i][j] = __builtin_amdgcn_mfma_f32_16x16x32_bf16(
                        af[i], bfr[j], acc[i][j], 0, 0, 0);
        }
        __syncthreads();
    }

    #pragma unroll
    for (int j = 0; j < 4; j++) {
        const int col = n0 + wc * 64 + j * 16 + l16;
        const float bv = bias[col];
        #pragma unroll
        for (int i = 0; i < 4; i++) {
            #pragma unroll
            for (int r = 0; r < 4; r++) {
                const int row = m0 + wr * 64 + i * 16 + quad * 4 + r;
                float v = alpha * (acc[i][j][r] + bv);
                if constexpr (std::is_same<OT, float>::value)
                    out[(size_t)row * CH + col] = v;
                else
                    out[(size_t)row * CH + col] = __float2bfloat16(v);
            }
        }
    }
}

// Batched Q+K projections (blockIdx.z selects operand set).
__global__ __launch_bounds__(256) void gemm_qk(
    const __hip_bfloat16* __restrict__ A0, const __hip_bfloat16* __restrict__ W0,
    const float* __restrict__ b0, __hip_bfloat16* __restrict__ o0, float alpha0,
    const __hip_bfloat16* __restrict__ A1, const __hip_bfloat16* __restrict__ W1,
    const float* __restrict__ b1, __hip_bfloat16* __restrict__ o1)
{
    __shared__ alignas(16) __hip_bfloat16 As[128 * 64];
    __shared__ alignas(16) __hip_bfloat16 Bs[128 * 64];
    if (blockIdx.z == 0)
        gemm_body<__hip_bfloat16>(A0, W0, b0, o0, alpha0, As, Bs);
    else
        gemm_body<__hip_bfloat16>(A1, W1, b1, o1, 1.0f, As, Bs);
}

template<typename OT>
__global__ __launch_bounds__(256) void gemm_one(
    const __hip_bfloat16* __restrict__ A, const __hip_bfloat16* __restrict__ Wb,
    const float* __restrict__ bias, OT* __restrict__ out)
{
    __shared__ alignas(16) __hip_bfloat16 As[128 * 64];
    __shared__ alignas(16) __hip_bfloat16 Bs[128 * 64];
    gemm_body<OT>(A, Wb, bias, out, 1.0f, As, Bs);
}

// One workgroup per (b, h, block-of-64-queries). Window of 192 keys
// starting at t0-64 (clamped loads, analytic masking).
__global__ __launch_bounds__(256) void attn_kernel(
    const __hip_bfloat16* __restrict__ qg,
    const __hip_bfloat16* __restrict__ kg,
    const __hip_bfloat16* __restrict__ vg,
    __hip_bfloat16* __restrict__ ctx)
{
    __shared__ alignas(16) char smem[62464];
    auto qs = reinterpret_cast<__hip_bfloat16(*)[72]>(smem);
    auto ks = reinterpret_cast<__hip_bfloat16(*)[72]>(smem + 9216);
    auto vt = reinterpret_cast<__hip_bfloat16(*)[200]>(smem + 36864);
    auto ps = reinterpret_cast<__hip_bfloat16(*)[200]>(smem);

    const int blk = blockIdx.x;
    const int n = blk & (NBL - 1);
    const int h = (blk >> 7) & (NH - 1);
    const int b = blk >> 11;
    const int t0  = n * BLK;
    const int kst = t0 - 64;
    const int tid = threadIdx.x;
    const size_t baseBH = (size_t)b * SEQ * CH + (size_t)h * DH;

    #pragma unroll
    for (int it = 0; it < 2; it++) {
        int c = tid + it * 256;
        int row = c >> 3, seg = c & 7;
        *reinterpret_cast<uint4*>(&qs[row][seg * 8]) =
            *reinterpret_cast<const uint4*>(qg + baseBH + (size_t)(t0 + row) * CH + seg * 8);
    }
    #pragma unroll
    for (int it = 0; it < 6; it++) {
        int c = tid + it * 256;
        int row = c >> 3, seg = c & 7;
        int tr = kst + row; tr = tr < 0 ? 0 : (tr >= SEQ ? SEQ - 1 : tr);
        *reinterpret_cast<uint4*>(&ks[row][seg * 8]) =
            *reinterpret_cast<const uint4*>(kg + baseBH + (size_t)tr * CH + seg * 8);
    }
    #pragma unroll
    for (int it = 0; it < 6; it++) {
        int c = tid + it * 256;
        int j = c % WIN, seg = c / WIN;
        int tr = kst + j; tr = tr < 0 ? 0 : (tr >= SEQ ? SEQ - 1 : tr);
        Pack8 p;
        p.u = *reinterpret_cast<const uint4*>(vg + baseBH + (size_t)tr * CH + seg * 8);
        #pragma unroll
        for (int e = 0; e < 8; e++) vt[seg * 8 + e][j] = p.h[e];
    }
    __syncthreads();

    const int wid = tid >> 6, lane = tid & 63, quad = lane >> 4, l16 = lane & 15;

    f32x4 sc[12];
    #pragma unroll
    for (int j = 0; j < 12; j++) sc[j] = zero4();
    #pragma unroll
    for (int kk = 0; kk < 2; kk++) {
        bf16x8 aq = *reinterpret_cast<const bf16x8*>(&qs[wid * 16 + l16][kk * 32 + quad * 8]);
        #pragma unroll
        for (int j = 0; j < 12; j++) {
            bf16x8 bk = *reinterpret_cast<const bf16x8*>(&ks[j * 16 + l16][kk * 32 + quad * 8]);
            sc[j] = __builtin_amdgcn_mfma_f32_16x16x32_bf16(aq, bk, sc[j], 0, 0, 0);
        }
    }
    __syncthreads();

    #pragma unroll
    for (int r = 0; r < 4; r++) {
        float s[12];
        float mx = -3.0e38f;
        #pragma unroll
        for (int j = 0; j < 12; j++) {
            int col = j * 16 + l16;
            int tr = kst + col;
            bool valid = (tr >= 0) && (tr < SEQ);
            s[j] = valid ? sc[j][r] : -3.0e38f;
            mx = fmaxf(mx, s[j]);
        }
        #pragma unroll
        for (int o = 1; o < 16; o <<= 1) mx = fmaxf(mx, __shfl_xor(mx, o, 64));
        float sum = 0.f;
        #pragma unroll
        for (int j = 0; j < 12; j++) {
            float e = __expf(s[j] - mx);
            s[j] = e;
            sum += e;
        }
        #pragma unroll
        for (int o = 1; o < 16; o <<= 1) sum += __shfl_xor(sum, o, 64);
        const float inv = 1.f / sum;
        const int row = wid * 16 + quad * 4 + r;
        #pragma unroll
        for (int j = 0; j < 12; j++)
            ps[row][j * 16 + l16] = __float2bfloat16(s[j] * inv);
    }
    __syncthreads();

    f32x4 oa[4];
    #pragma unroll
    for (int j = 0; j < 4; j++) oa[j] = zero4();
    #pragma unroll
    for (int kk = 0; kk < 6; kk++) {
        bf16x8 ap = *reinterpret_cast<const bf16x8*>(&ps[wid * 16 + l16][kk * 32 + quad * 8]);
        #pragma unroll
        for (int j = 0; j < 4; j++) {
            bf16x8 bv = *reinterpret_cast<const bf16x8*>(&vt[j * 16 + l16][kk * 32 + quad * 8]);
            oa[j] = __builtin_amdgcn_mfma_f32_16x16x32_bf16(ap, bv, oa[j], 0, 0, 0);
        }
    }
    #pragma unroll
    for (int j = 0; j < 4; j++) {
        const int d = j * 16 + l16;
        #pragma unroll
        for (int r = 0; r < 4; r++) {
            const int i = wid * 16 + quad * 4 + r;
            ctx[baseBH + (size_t)(t0 + i) * CH + d] = __float2bfloat16(oa[j][r]);
        }
    }
}

extern "C" void kernel_launch(void* const* d_in, const int* in_sizes, int n_in,
                              void* d_out, int out_size, void* d_ws, size_t ws_size,
                              hipStream_t stream)
{
    const float* query = (const float*)d_in[0];
    const float* key_i = (const float*)d_in[1];
    const float* value = (const float*)d_in[2];
    const float* Wq = (const float*)d_in[3];
    const float* bq = (const float*)d_in[4];
    const float* Wk = (const float*)d_in[5];
    const float* bk = (const float*)d_in[6];
    const float* Wv = (const float*)d_in[7];
    const float* bv = (const float*)d_in[8];
    const float* Wo = (const float*)d_in[9];
    const float* bo = (const float*)d_in[10];
    float* out = (float*)d_out;

    const size_t NELEM = (size_t)MR * CH;   // 16,777,216
    const size_t WELEM = (size_t)CH * CH;   // 1,048,576

    // ws layout (104 MiB):
    //   S0: xv (phase 1-2) -> cb (phase 3-4)
    //   S1: qb   S2: kb
    //   S3: packed weights wq|wk|wv|wo (2 MiB each)
    __hip_bfloat16* S0 = (__hip_bfloat16*)d_ws;
    __hip_bfloat16* S1 = S0 + NELEM;
    __hip_bfloat16* S2 = S1 + NELEM;
    __hip_bfloat16* S3 = S2 + NELEM;
    __hip_bfloat16* wqb = S3;
    __hip_bfloat16* wkb = S3 + WELEM;
    __hip_bfloat16* wvb = S3 + 2 * WELEM;
    __hip_bfloat16* wob = S3 + 3 * WELEM;

    // d_out doubles as scratch: xq|xk (bf16) until consumed, then vb.
    __hip_bfloat16* xq = (__hip_bfloat16*)d_out;
    __hip_bfloat16* xk = xq + NELEM;
    __hip_bfloat16* vb = (__hip_bfloat16*)d_out;   // after QK-GEMM consumed xq/xk
    __hip_bfloat16* qb = S1;
    __hip_bfloat16* kb = S2;
    __hip_bfloat16* cb = S0;

    const int nA8 = (int)(NELEM / 8);
    const int nW8 = (int)(WELEM / 8);

    pack_bf16<<<nA8 / 256, 256, 0, stream>>>(query, xq, nA8);
    pack_bf16<<<nA8 / 256, 256, 0, stream>>>(key_i, xk, nA8);
    pack_bf16<<<nA8 / 256, 256, 0, stream>>>(value, S0, nA8);
    pack_bf16<<<nW8 / 256, 256, 0, stream>>>(Wq, wqb, nW8);
    pack_bf16<<<nW8 / 256, 256, 0, stream>>>(Wk, wkb, nW8);
    pack_bf16<<<nW8 / 256, 256, 0, stream>>>(Wv, wvb, nW8);
    pack_bf16<<<nW8 / 256, 256, 0, stream>>>(Wo, wob, nW8);

    dim3 ggrid(CH / 128, MR / 128);         // (8, 128)
    dim3 qkgrid(CH / 128, MR / 128, 2);     // 2048 blocks

    gemm_qk<<<qkgrid, 256, 0, stream>>>(xq, wqb, bq, qb, 0.125f,
                                        xk, wkb, bk, kb);
    gemm_one<__hip_bfloat16><<<ggrid, 256, 0, stream>>>(S0, wvb, bv, vb);

    attn_kernel<<<BATCH * NH * NBL, 256, 0, stream>>>(qb, kb, vb, cb);

    gemm_one<float><<<ggrid, 256, 0, stream>>>(cb, wob, bo, out);
}